// Round 4
// baseline (863.493 us; speedup 1.0000x reference)
//
#include <hip/hip_runtime.h>
#include <cstdint>
#include <cstddef>

#define B_DIM  16
#define S_BANK 8192
#define S_REF  32
#define S_TOT  8224   // S_BANK + S_REF
#define NMERGE 32     // S_TOT - MAX_SLOTS
#define D      512
#define NCH    129    // ceil(S_TOT / 64)

typedef float vfloat4 __attribute__((ext_vector_type(4)));  // NT-store capable

// ---------------- DPP wave64 reductions (VALU pipe, no ds_bpermute) ----------
__device__ __forceinline__ int d_lo(double d){ union{double d; int i[2];}u; u.d=d; return u.i[0]; }
__device__ __forceinline__ int d_hi(double d){ union{double d; int i[2];}u; u.d=d; return u.i[1]; }
__device__ __forceinline__ double d_mk(int hi,int lo){ union{double d; int i[2];}u; u.i[0]=lo;u.i[1]=hi; return u.d; }

template<int CTRL>
__device__ __forceinline__ void lex_level(double& v, int& j) {
    // old = self, bound_ctrl = 0: invalid lanes keep own value (lexmin idempotent)
    int lo2 = __builtin_amdgcn_update_dpp(d_lo(v), d_lo(v), CTRL, 0xF, 0xF, false);
    int hi2 = __builtin_amdgcn_update_dpp(d_hi(v), d_hi(v), CTRL, 0xF, 0xF, false);
    int j2  = __builtin_amdgcn_update_dpp(j,       j,       CTRL, 0xF, 0xF, false);
    double v2 = d_mk(hi2, lo2);
    if (v2 < v || (v2 == v && j2 < j)) { v = v2; j = j2; }
}
// lexmin over 64 lanes; result broadcast to all lanes (assoc+comm => exact)
__device__ __forceinline__ void lexmin_wave(double& v, int& j) {
    lex_level<0x111>(v, j);  // row_shr:1
    lex_level<0x112>(v, j);  // row_shr:2
    lex_level<0x114>(v, j);  // row_shr:4
    lex_level<0x118>(v, j);  // row_shr:8
    lex_level<0x142>(v, j);  // row_bcast:15
    lex_level<0x143>(v, j);  // row_bcast:31  -> lane 63 holds lexmin
    int lo = __builtin_amdgcn_readlane(d_lo(v), 63);
    int hi = __builtin_amdgcn_readlane(d_hi(v), 63);
    j      = __builtin_amdgcn_readlane(j, 63);
    v = d_mk(hi, lo);
}
template<int CTRL>
__device__ __forceinline__ void sum_level(double& v) {
    // bound_ctrl = 1: invalid lanes contribute +0.0
    int lo2 = __builtin_amdgcn_update_dpp(0, d_lo(v), CTRL, 0xF, 0xF, true);
    int hi2 = __builtin_amdgcn_update_dpp(0, d_hi(v), CTRL, 0xF, 0xF, true);
    v += d_mk(hi2, lo2);
}
__device__ __forceinline__ double sum_wave(double v) {
    sum_level<0x111>(v); sum_level<0x112>(v); sum_level<0x114>(v);
    sum_level<0x118>(v); sum_level<0x142>(v); sum_level<0x143>(v);
    int lo = __builtin_amdgcn_readlane(d_lo(v), 63);
    int hi = __builtin_amdgcn_readlane(d_hi(v), 63);
    return d_mk(hi, lo);
}

// ---------------- Kernel 1: per-slot L2 norms (f64), reverse order -----------
__global__ __launch_bounds__(256) void norms_kernel(const float* __restrict__ bank,
                                                    const float* __restrict__ refresh,
                                                    double* __restrict__ norms) {
    int gw_lin = (int)((blockIdx.x * 256 + threadIdx.x) >> 6);
    int gw   = B_DIM * S_TOT - 1 - gw_lin;
    int lane = threadIdx.x & 63;
    int b = gw / S_TOT;
    int s = gw - b * S_TOT;
    const float4* src = (const float4*)(s < S_BANK
        ? bank    + ((size_t)b * S_BANK + s) * D
        : refresh + ((size_t)b * S_REF + (s - S_BANK)) * D);
    float4 f0 = src[lane];
    float4 f1 = src[lane + 64];
    double acc = 0.0;
    acc += (double)f0.x * f0.x + (double)f0.y * f0.y + (double)f0.z * f0.z + (double)f0.w * f0.w;
    acc += (double)f1.x * f1.x + (double)f1.y * f1.y + (double)f1.z * f1.z + (double)f1.w * f1.w;
    acc = sum_wave(acc);
    if (lane == 0) norms[gw] = sqrt(acc);
}

// ---------------- Kernel 2: merge-v6 — speculative parent prefetch ----------
__device__ __forceinline__ const float* slot_gptr(int id, int b,
        const float* bank, const float* refresh) {
    return (id < S_BANK) ? bank    + ((size_t)b * S_BANK + id) * D
                         : refresh + ((size_t)b * S_REF + (id - S_BANK)) * D;
}

__global__ __launch_bounds__(256) void merge_kernel(const float* __restrict__ bank,
        const float* __restrict__ refresh, const double* __restrict__ norms,
        float* __restrict__ merged, unsigned short* __restrict__ idx_out) {
    __shared__ double         s_imp[S_TOT];      // >=1e300 == dead
    __shared__ unsigned short s_next[S_TOT];     // reused as id-LUT later
    __shared__ float          s_mvec[NMERGE][D]; // merged vectors
    __shared__ unsigned short s_mpos[NMERGE];
    __shared__ unsigned short s_dead[NMERGE];
    __shared__ double c_val[NCH];
    __shared__ int    c_idx[NCH];

    const int t    = threadIdx.x;
    const int b    = blockIdx.x;
    const int lane = t & 63;
    const int wid  = t >> 6;     // 4 waves
    const double INF = __builtin_inf();

    int mpos_reg = -1;           // lane l: position of merge result l (register copy)

    // speculative-prefetch carried state (cascade fast path)
    int prev_p = -1, prev_pv = -1, prev_nk = -1;
    int pvok = 0, nkok = 0;
    float4 mm0, mm1;             // previous merged vector (slot prev_p's current vec)
    float4 pva0, pva1;           // prefetched vector of prev_pv
    float4 pnk0, pnk1;           // prefetched vector of prev_nk

    for (int j = t; j < S_TOT; j += 256) {
        s_imp[j]  = norms[b * S_TOT + j];
        s_next[j] = (unsigned short)((j + 1 < S_TOT) ? (j + 1) : 0xFFFF);
    }
    __syncthreads();

    // initial chunk minima: one thread per chunk, serial scan
    if (t < NCH) {
        int j0 = t * 64;
        int jend = (j0 + 63 < S_TOT - 1) ? (j0 + 63) : (S_TOT - 2);
        double best = INF; int bj = 0x7FFFFFFF;
        for (int j = j0; j <= jend; ++j) {
            double sc = s_imp[j] + s_imp[j + 1];
            if (sc < best) { best = sc; bj = j; }
        }
        c_val[t] = best; c_idx[t] = bj;
    }
    __syncthreads();

    for (int step = 0; step < NMERGE; ++step) {
        // ======== phase A (every wave redundantly; deterministic => agree) ====
        double v = c_val[lane]; int j = c_idx[lane];
        {
            double v2 = c_val[lane + 64]; int j2 = c_idx[lane + 64];
            if (v2 < v || (v2 == v && j2 < j)) { v = v2; j = j2; }
        }
        if (lane == 0) {
            double v3 = c_val[128]; int j3 = c_idx[128];
            if (v3 < v || (v3 == v && j3 < j)) { v = v3; j = j3; }
        }
        lexmin_wave(v, j);
        const int p = j;

        // cascade fast paths: winner involves last step's merged slot
        const bool hitA = pvok && (p == prev_pv);   // pair (prev_pv, prev_p)
        const bool hitB = nkok && (p == prev_p);    // pair (prev_p, prev_nk)

        int k, nk;
        float4 a0, a1, b0, b1;
        if (hitA) {
            k  = prev_p;                 // s_next[prev_pv] == prev_p (list invariant)
            nk = prev_nk;                // s_next[prev_p] == prev_nk (post-commit)
            a0 = pva0; a1 = pva1;        // pv vector: prefetched
            b0 = mm0;  b1 = mm1;         // prev_p vector: carried merged regs
        } else if (hitB) {
            k  = prev_nk;
            nk = s_next[k];              // off critical path (needed for rescan/commit)
            a0 = mm0;  a1 = mm1;
            b0 = pnk0; b1 = pnk1;        // nk vector: prefetched
        } else {
            k  = s_next[p];              // uniform LDS broadcast
            nk = s_next[k];
            // identities from register mpos (no LDS read)
            unsigned long long bA = __ballot((lane < step) && (mpos_reg == p));
            const int ia = bA ? (S_TOT + 63 - __clzll(bA)) : p;
            unsigned long long bB = __ballot((lane < step) && (mpos_reg == k));
            const int ib = bB ? (S_TOT + 63 - __clzll(bB)) : k;
            if (ia < S_TOT) { const float4* g = (const float4*)slot_gptr(ia, b, bank, refresh);
                              a0 = g[2 * lane]; a1 = g[2 * lane + 1]; }
            else            { const float4* g = (const float4*)&s_mvec[ia - S_TOT][0];
                              a0 = g[2 * lane]; a1 = g[2 * lane + 1]; }
            if (ib < S_TOT) { const float4* g = (const float4*)slot_gptr(ib, b, bank, refresh);
                              b0 = g[2 * lane]; b1 = g[2 * lane + 1]; }
            else            { const float4* g = (const float4*)&s_mvec[ib - S_TOT][0];
                              b0 = g[2 * lane]; b1 = g[2 * lane + 1]; }
        }

        // prev-live slot before p (known when hitB; otherwise ballot scan)
        int pv;
        if (hitB) {
            pv = prev_pv;                // nothing between pv and p changed liveness
        } else {
            int jq = p - 1 - lane;
            bool plive = (jq >= 0) && (s_imp[jq] < 1e300);
            unsigned long long pb = __ballot(plive);
            pv = pb ? (p - __ffsll((unsigned long long)pb)) : -1;
        }

        float4 m0, m1;
        m0.x = 0.5f * (a0.x + b0.x); m0.y = 0.5f * (a0.y + b0.y);
        m0.z = 0.5f * (a0.z + b0.z); m0.w = 0.5f * (a0.w + b0.w);
        m1.x = 0.5f * (a1.x + b1.x); m1.y = 0.5f * (a1.y + b1.y);
        m1.z = 0.5f * (a1.z + b1.z); m1.w = 0.5f * (a1.w + b1.w);
        if (wid == 0) {
            float4* dst = (float4*)&s_mvec[step][0];
            dst[2 * lane] = m0; dst[2 * lane + 1] = m1;
        }
        double ss = 0.0;
        ss += (double)m0.x * m0.x + (double)m0.y * m0.y + (double)m0.z * m0.z + (double)m0.w * m0.w;
        ss += (double)m1.x * m1.x + (double)m1.y * m1.y + (double)m1.z * m1.z + (double)m1.w * m1.w;
        const double nrm = sqrt(sum_wave(ss));
        if (lane == step) mpos_reg = p;      // register mpos update (all waves)
        __syncthreads();                     // ---- B1 ----

        // ======== phase B ====================================================
        if (wid == 3 && lane == 0) {         // commit (concurrent with rescans)
            s_next[p]    = (unsigned short)nk;
            s_imp[k]     = INF;
            s_imp[p]     = nrm;
            s_mpos[step] = (unsigned short)p;
            s_dead[step] = (unsigned short)k;
        }

        // ---- speculative prefetch of next step's likely parents (all waves) --
        // Next merge is overwhelmingly (pv, p) or (p, nk): the merged slot's
        // norm drops well below the population, so scores around p stay minimal.
        if (step + 1 < NMERGE) {
            prev_p  = p;
            prev_pv = pv;
            prev_nk = nk;
            mm0 = m0; mm1 = m1;
            pvok = (pv >= 0);
            nkok = (nk != 0xFFFF);
            // identity resolution incl. current step (mpos can't equal pv or nk,
            // both differ from p, so s_mvec[step] is never read here -> no race)
            unsigned long long bpv = __ballot((lane <= step) && (mpos_reg == pv));
            const int ipv = bpv ? (S_TOT + 63 - __clzll(bpv)) : pv;
            unsigned long long bnk = __ballot((lane <= step) && (mpos_reg == nk));
            const int ink = bnk ? (S_TOT + 63 - __clzll(bnk)) : nk;
            if (pvok) {
                if (ipv < S_TOT) { const float4* g = (const float4*)slot_gptr(ipv, b, bank, refresh);
                                   pva0 = g[2 * lane]; pva1 = g[2 * lane + 1]; }
                else             { const float4* g = (const float4*)&s_mvec[ipv - S_TOT][0];
                                   pva0 = g[2 * lane]; pva1 = g[2 * lane + 1]; }
            }
            if (nkok) {
                if (ink < S_TOT) { const float4* g = (const float4*)slot_gptr(ink, b, bank, refresh);
                                   pnk0 = g[2 * lane]; pnk1 = g[2 * lane + 1]; }
                else             { const float4* g = (const float4*)&s_mvec[ink - S_TOT][0];
                                   pnk0 = g[2 * lane]; pnk1 = g[2 * lane + 1]; }
            }
        }

        if (wid < 3) {                       // rescan affected chunks, stale LDS
            int chp = p >> 6, chk = k >> 6;  // + in-register substitutions
            int chv = (pv >= 0) ? (pv >> 6) : -1;
            int cs = (wid == 0) ? chp
                   : (wid == 1) ? ((chk != chp) ? chk : -1)
                                : ((chv >= 0 && chv != chp && chv != chk) ? chv : -1);
            if (cs >= 0) {
                double sc = INF; int bj = 0x7FFFFFFF;
                int jj = cs * 64 + lane;
                if (jj < S_TOT && jj != k) {
                    int nxt = (jj == p) ? nk : (int)s_next[jj];
                    if (nxt != 0xFFFF) {
                        double a0d = (jj == p) ? nrm : s_imp[jj];
                        if (a0d < 1e300) {
                            double a1d = (nxt == p) ? nrm : s_imp[nxt];
                            sc = a0d + a1d; bj = jj;
                        }
                    }
                }
                lexmin_wave(sc, bj);
                if (lane == 0) { c_val[cs] = sc; c_idx[cs] = bj; }
            }
        }
        __syncthreads();                     // ---- B2 ----
    }

    // ---- dump merged vectors to global for the gather ----
    {
        const float4* src = (const float4*)&s_mvec[0][0];
        float4* dst = (float4*)(merged + (size_t)b * NMERGE * D);
        for (int i = t; i < NMERGE * D / 4; i += 256) dst[i] = src[i];
    }

    // ---- identity LUT in s_next (dead after main loop) ----
    for (int j = t; j < S_TOT; j += 256) s_next[j] = 0xFFFF;
    __syncthreads();
    if (t == 0)
        for (int m2 = 0; m2 < NMERGE; ++m2) s_next[s_mpos[m2]] = (unsigned short)m2;
    __syncthreads();

    // ---- emit compacted index map ----
    for (int j = t; j < S_TOT; j += 256) {
        if (s_imp[j] < 1e300) {
            int r = j;
            #pragma unroll
            for (int m2 = 0; m2 < NMERGE; ++m2) r -= (s_dead[m2] < j) ? 1 : 0;
            unsigned short lut = s_next[j];
            idx_out[b * S_BANK + r] = (lut != 0xFFFF) ? (unsigned short)(S_TOT + lut)
                                                      : (unsigned short)j;
        }
    }
}

// ---------------- Kernel 3: gather/write output (float4, NT stores) ----------
__global__ __launch_bounds__(256) void gather_kernel(const vfloat4* __restrict__ bank,
        const vfloat4* __restrict__ refresh, const vfloat4* __restrict__ merged,
        const unsigned short* __restrict__ idx, vfloat4* __restrict__ out) {
    size_t tid = (size_t)blockIdx.x * 256 + threadIdx.x;
    int slot = (int)(tid >> 7);
    int c    = (int)(tid & 127);
    int b    = slot >> 13;
    int src  = idx[slot];
    const vfloat4* sp;
    if (src < S_BANK)     sp = bank    + ((size_t)b * S_BANK + src) * (D / 4);
    else if (src < S_TOT) sp = refresh + ((size_t)b * S_REF + (src - S_BANK)) * (D / 4);
    else                  sp = merged  + ((size_t)b * NMERGE + (src - S_TOT)) * (D / 4);
    vfloat4 v = sp[c];
    __builtin_nontemporal_store(v, &out[tid]);
}

// ------------------------------------------------------------------------------
// INSTRUMENTATION ROUND: merge_kernel launched 9x (idempotent — reads only
// bank/refresh/norms, deterministically overwrites merged/idx_out).
// dur_us = base(203) + 8 * t_merge  =>  t_merge = (dur_us - 203) / 8.
extern "C" void kernel_launch(void* const* d_in, const int* in_sizes, int n_in,
                              void* d_out, int out_size, void* d_ws, size_t ws_size,
                              hipStream_t stream) {
    const float* bank    = (const float*)d_in[0];
    const float* refresh = (const float*)d_in[1];

    double*         norms  = (double*)d_ws;
    float*          merged = (float*)((char*)d_ws + (size_t)B_DIM * S_TOT * sizeof(double));
    unsigned short* idx    = (unsigned short*)((char*)merged + (size_t)B_DIM * NMERGE * D * sizeof(float));
    float*          out    = (float*)d_out;

    norms_kernel<<<(B_DIM * S_TOT) / 4, 256, 0, stream>>>(bank, refresh, norms);
    for (int rep = 0; rep < 9; ++rep)
        merge_kernel<<<B_DIM, 256, 0, stream>>>(bank, refresh, norms, merged, idx);
    gather_kernel<<<(size_t)B_DIM * S_BANK * (D / 4) / 256, 256, 0, stream>>>(
        (const vfloat4*)bank, (const vfloat4*)refresh, (const vfloat4*)merged, idx, (vfloat4*)out);
}

// Round 5
// 203.097 us; speedup vs baseline: 4.2516x; 4.2516x over previous
//
#include <hip/hip_runtime.h>
#include <cstdint>
#include <cstddef>

#define B_DIM  16
#define S_BANK 8192
#define S_REF  32
#define S_TOT  8224   // S_BANK + S_REF
#define NMERGE 32     // S_TOT - MAX_SLOTS
#define D      512
#define NCH    129    // ceil(S_TOT / 64)

typedef float vfloat4 __attribute__((ext_vector_type(4)));  // NT-store capable

// ---------------- DPP wave64 reductions (VALU pipe, no ds_bpermute) ----------
__device__ __forceinline__ int d_lo(double d){ union{double d; int i[2];}u; u.d=d; return u.i[0]; }
__device__ __forceinline__ int d_hi(double d){ union{double d; int i[2];}u; u.d=d; return u.i[1]; }
__device__ __forceinline__ double d_mk(int hi,int lo){ union{double d; int i[2];}u; u.i[0]=lo;u.i[1]=hi; return u.d; }

template<int CTRL>
__device__ __forceinline__ void lex_level(double& v, int& j) {
    // old = self, bound_ctrl = 0: invalid lanes keep own value (lexmin idempotent)
    int lo2 = __builtin_amdgcn_update_dpp(d_lo(v), d_lo(v), CTRL, 0xF, 0xF, false);
    int hi2 = __builtin_amdgcn_update_dpp(d_hi(v), d_hi(v), CTRL, 0xF, 0xF, false);
    int j2  = __builtin_amdgcn_update_dpp(j,       j,       CTRL, 0xF, 0xF, false);
    double v2 = d_mk(hi2, lo2);
    if (v2 < v || (v2 == v && j2 < j)) { v = v2; j = j2; }
}
// lexmin over 64 lanes; result broadcast to all lanes (assoc+comm => exact)
__device__ __forceinline__ void lexmin_wave(double& v, int& j) {
    lex_level<0x111>(v, j);  // row_shr:1
    lex_level<0x112>(v, j);  // row_shr:2
    lex_level<0x114>(v, j);  // row_shr:4
    lex_level<0x118>(v, j);  // row_shr:8
    lex_level<0x142>(v, j);  // row_bcast:15
    lex_level<0x143>(v, j);  // row_bcast:31  -> lane 63 holds lexmin
    int lo = __builtin_amdgcn_readlane(d_lo(v), 63);
    int hi = __builtin_amdgcn_readlane(d_hi(v), 63);
    j      = __builtin_amdgcn_readlane(j, 63);
    v = d_mk(hi, lo);
}
template<int CTRL>
__device__ __forceinline__ void sum_level(double& v) {
    // bound_ctrl = 1: invalid lanes contribute +0.0
    int lo2 = __builtin_amdgcn_update_dpp(0, d_lo(v), CTRL, 0xF, 0xF, true);
    int hi2 = __builtin_amdgcn_update_dpp(0, d_hi(v), CTRL, 0xF, 0xF, true);
    v += d_mk(hi2, lo2);
}
__device__ __forceinline__ double sum_wave(double v) {
    sum_level<0x111>(v); sum_level<0x112>(v); sum_level<0x114>(v);
    sum_level<0x118>(v); sum_level<0x142>(v); sum_level<0x143>(v);
    int lo = __builtin_amdgcn_readlane(d_lo(v), 63);
    int hi = __builtin_amdgcn_readlane(d_hi(v), 63);
    return d_mk(hi, lo);
}

// ---------------- Kernel 1: per-slot L2 norms (f64), reverse order -----------
__global__ __launch_bounds__(256) void norms_kernel(const float* __restrict__ bank,
                                                    const float* __restrict__ refresh,
                                                    double* __restrict__ norms) {
    int gw_lin = (int)((blockIdx.x * 256 + threadIdx.x) >> 6);
    int gw   = B_DIM * S_TOT - 1 - gw_lin;
    int lane = threadIdx.x & 63;
    int b = gw / S_TOT;
    int s = gw - b * S_TOT;
    const float4* src = (const float4*)(s < S_BANK
        ? bank    + ((size_t)b * S_BANK + s) * D
        : refresh + ((size_t)b * S_REF + (s - S_BANK)) * D);
    float4 f0 = src[lane];
    float4 f1 = src[lane + 64];
    double acc = 0.0;
    acc += (double)f0.x * f0.x + (double)f0.y * f0.y + (double)f0.z * f0.z + (double)f0.w * f0.w;
    acc += (double)f1.x * f1.x + (double)f1.y * f1.y + (double)f1.z * f1.z + (double)f1.w * f1.w;
    acc = sum_wave(acc);
    if (lane == 0) norms[gw] = sqrt(acc);
}

// ---------------- Kernel 2: merge-v8 — s_score + register chunk minima -------
__device__ __forceinline__ const float* slot_gptr(int id, int b,
        const float* bank, const float* refresh) {
    return (id < S_BANK) ? bank    + ((size_t)b * S_BANK + id) * D
                         : refresh + ((size_t)b * S_REF + (id - S_BANK)) * D;
}

__global__ __launch_bounds__(256) void merge_kernel(const float* __restrict__ bank,
        const float* __restrict__ refresh, const double* __restrict__ norms,
        float* __restrict__ merged, unsigned short* __restrict__ idx_out) {
    __shared__ double         s_imp[S_TOT];      // >=1e300 == dead
    __shared__ double         s_score[S_TOT];    // imp[j] + imp[next[j]]; INF if no pair
    __shared__ unsigned short s_next[S_TOT];     // reused as id-LUT later
    __shared__ unsigned short s_mpos[NMERGE];
    __shared__ unsigned short s_dead[NMERGE];
    __shared__ double c_val[NCH];                // init only; registers thereafter
    __shared__ int    c_idx[NCH];

    const int t    = threadIdx.x;
    const int b    = blockIdx.x;
    const int lane = t & 63;
    const int wid  = t >> 6;     // 4 waves
    const double INF = __builtin_inf();

    int mpos_reg = -1;           // lane l: position of merge result l (register copy)

    // speculative-prefetch carried state (cascade fast path)
    int prev_p = -1, prev_pv = -1, prev_nk = -1;
    int pvok = 0, nkok = 0;
    float4 mm0, mm1;             // previous merged vector (slot prev_p's current vec)
    float4 pva0, pva1;           // prefetched vector of prev_pv
    float4 pnk0, pnk1;           // prefetched vector of prev_nk

    for (int j = t; j < S_TOT; j += 256) {
        s_imp[j]  = norms[b * S_TOT + j];
        s_next[j] = (unsigned short)((j + 1 < S_TOT) ? (j + 1) : 0xFFFF);
    }
    __syncthreads();
    // score array (same f64 add order as the v6 rescan: imp[j] + imp[next[j]])
    for (int j = t; j < S_TOT; j += 256)
        s_score[j] = (j + 1 < S_TOT) ? (s_imp[j] + s_imp[j + 1]) : INF;
    __syncthreads();

    // initial chunk minima: one thread per chunk, serial scan of s_score
    if (t < NCH) {
        int j0 = t * 64;
        double best = INF; int bj = 0x7FFFFFFF;
        for (int j = j0; j < j0 + 64; ++j) {
            double sc = s_score[(j < S_TOT) ? j : (S_TOT - 1)];  // clamped; tail is INF
            if (j >= S_TOT) sc = INF;
            if (sc < best) { best = sc; bj = j; }
        }
        c_val[t] = best; c_idx[t] = bj;
    }
    __syncthreads();

    // register-resident chunk minima, replicated on every wave
    double cv0 = c_val[lane];      int cj0 = c_idx[lane];
    double cv1 = c_val[lane + 64]; int cj1 = c_idx[lane + 64];
    double cv2 = (lane == 0) ? c_val[128] : INF;
    int    cj2 = (lane == 0) ? c_idx[128] : 0x7FFFFFFF;

    for (int step = 0; step < NMERGE; ++step) {
        // ======== phase A: pure-register argmin + one DPP lexmin =============
        double v = cv0; int j = cj0;
        if (cv1 < v || (cv1 == v && cj1 < j)) { v = cv1; j = cj1; }
        if (cv2 < v || (cv2 == v && cj2 < j)) { v = cv2; j = cj2; }
        lexmin_wave(v, j);
        const int p = j;

        // cascade fast paths: winner involves last step's merged slot
        const bool hitA = pvok && (p == prev_pv);   // pair (prev_pv, prev_p)
        const bool hitB = nkok && (p == prev_p);    // pair (prev_p, prev_nk)

        int k, nk;
        float4 a0, a1, b0, b1;
        if (hitA) {
            k  = prev_p;                 // s_next[prev_pv] == prev_p (list invariant)
            nk = prev_nk;                // s_next[prev_p] == prev_nk (post-commit)
            a0 = pva0; a1 = pva1;        // pv vector: prefetched
            b0 = mm0;  b1 = mm1;         // prev_p vector: carried merged regs
        } else if (hitB) {
            k  = prev_nk;
            nk = s_next[k];              // pre-B1 read of stable entry
            a0 = mm0;  a1 = mm1;
            b0 = pnk0; b1 = pnk1;        // nk vector: prefetched
        } else {
            k  = s_next[p];              // uniform LDS broadcast
            nk = s_next[k];
            // identities from register mpos (no LDS read)
            unsigned long long bA = __ballot((lane < step) && (mpos_reg == p));
            const int ia = bA ? (S_TOT + 63 - __clzll(bA)) : p;
            unsigned long long bB = __ballot((lane < step) && (mpos_reg == k));
            const int ib = bB ? (S_TOT + 63 - __clzll(bB)) : k;
            if (ia < S_TOT) { const float4* g = (const float4*)slot_gptr(ia, b, bank, refresh);
                              a0 = g[2 * lane]; a1 = g[2 * lane + 1]; }
            else            { const float4* g = (const float4*)(merged +
                                  ((size_t)b * NMERGE + (ia - S_TOT)) * D);
                              a0 = g[2 * lane]; a1 = g[2 * lane + 1]; }
            if (ib < S_TOT) { const float4* g = (const float4*)slot_gptr(ib, b, bank, refresh);
                              b0 = g[2 * lane]; b1 = g[2 * lane + 1]; }
            else            { const float4* g = (const float4*)(merged +
                                  ((size_t)b * NMERGE + (ib - S_TOT)) * D);
                              b0 = g[2 * lane]; b1 = g[2 * lane + 1]; }
        }

        // prev-live slot before p (known when hitB; otherwise ballot scan)
        int pv;
        if (hitB) {
            pv = prev_pv;                // nothing between pv and p changed liveness
        } else {
            int jq = p - 1 - lane;
            bool plive = (jq >= 0) && (s_imp[jq] < 1e300);
            unsigned long long pb = __ballot(plive);
            pv = pb ? (p - __ffsll((unsigned long long)pb)) : -1;
        }

        // ---- early LDS reads (pre-B1 == pre-commit: race-free, stale-OK) ----
        const double imp_nk = s_imp[(nk != 0xFFFF) ? nk : 0];  // valid iff nk valid
        const double imp_pv = s_imp[(pv >= 0) ? pv : 0];       // valid iff pv valid
        const int chp = p >> 6, chk = k >> 6;
        const int chv = (pv >= 0) ? (pv >> 6) : -1;
        const int csB = (chk != chp) ? chk : -1;
        const int csC = (chv >= 0 && chv != chp && chv != chk) ? chv : -1;
        const int jjA = chp * 64 + lane;
        const int jjB = ((csB >= 0) ? csB : 0) * 64 + lane;
        const int jjC = ((csC >= 0) ? csC : 0) * 64 + lane;
        const double rawA = s_score[(jjA < S_TOT) ? jjA : (S_TOT - 1)];
        const double rawB = s_score[(jjB < S_TOT) ? jjB : (S_TOT - 1)];
        const double rawC = s_score[(jjC < S_TOT) ? jjC : (S_TOT - 1)];

        // ---- merge + norm (identical arithmetic/order to v6) ----
        float4 m0, m1;
        m0.x = 0.5f * (a0.x + b0.x); m0.y = 0.5f * (a0.y + b0.y);
        m0.z = 0.5f * (a0.z + b0.z); m0.w = 0.5f * (a0.w + b0.w);
        m1.x = 0.5f * (a1.x + b1.x); m1.y = 0.5f * (a1.y + b1.y);
        m1.z = 0.5f * (a1.z + b1.z); m1.w = 0.5f * (a1.w + b1.w);
        if (wid == 0) {                  // merged vector straight to global (L2)
            float4* dst = (float4*)(merged + ((size_t)b * NMERGE + step) * D);
            dst[2 * lane] = m0; dst[2 * lane + 1] = m1;
        }
        double ss = 0.0;
        ss += (double)m0.x * m0.x + (double)m0.y * m0.y + (double)m0.z * m0.z + (double)m0.w * m0.w;
        ss += (double)m1.x * m1.x + (double)m1.y * m1.y + (double)m1.z * m1.z + (double)m1.w * m1.w;
        const double nrm = sqrt(sum_wave(ss));

        // new scores (same operand order a fresh v6 rescan would produce)
        const double score_p_new  = (nk != 0xFFFF) ? (nrm + imp_nk) : INF;
        const double score_pv_new = imp_pv + nrm;   // meaningful iff pv >= 0

        if (lane == step) mpos_reg = p;      // register mpos update (all waves)
        __syncthreads();                     // ---- B1: all old-state reads done ----

        // ======== phase B ====================================================
        if (wid == 3 && lane == 0) {         // commit (sole LDS writer this phase)
            s_next[p]    = (unsigned short)nk;
            s_imp[k]     = INF;
            s_imp[p]     = nrm;
            s_score[k]   = INF;
            s_score[p]   = score_p_new;
            if (pv >= 0) s_score[pv] = score_pv_new;
            s_mpos[step] = (unsigned short)p;
            s_dead[step] = (unsigned short)k;
        }

        // ---- rescan finalize: substitutions + lexmin, ALL waves (registers) --
        {
            double sc = rawA; int bj = jjA;
            if (jjA >= S_TOT) sc = INF;
            if (jjA == k)     sc = INF;
            if (jjA == p)     sc = score_p_new;
            if (pv >= 0 && jjA == pv) sc = score_pv_new;
            lexmin_wave(sc, bj);
            if (lane == (chp & 63)) {
                if (chp < 64)       { cv0 = sc; cj0 = bj; }
                else if (chp < 128) { cv1 = sc; cj1 = bj; }
                else                { if (lane == 0) { cv2 = sc; cj2 = bj; } }
            }
        }
        if (csB >= 0) {
            double sc = rawB; int bj = jjB;
            if (jjB >= S_TOT) sc = INF;
            if (jjB == k)     sc = INF;
            if (jjB == p)     sc = score_p_new;
            if (pv >= 0 && jjB == pv) sc = score_pv_new;
            lexmin_wave(sc, bj);
            if (lane == (csB & 63)) {
                if (csB < 64)       { cv0 = sc; cj0 = bj; }
                else if (csB < 128) { cv1 = sc; cj1 = bj; }
                else                { if (lane == 0) { cv2 = sc; cj2 = bj; } }
            }
        }
        if (csC >= 0) {
            double sc = rawC; int bj = jjC;
            if (jjC >= S_TOT) sc = INF;
            if (jjC == k)     sc = INF;
            if (jjC == p)     sc = score_p_new;
            if (pv >= 0 && jjC == pv) sc = score_pv_new;
            lexmin_wave(sc, bj);
            if (lane == (csC & 63)) {
                if (csC < 64)       { cv0 = sc; cj0 = bj; }
                else if (csC < 128) { cv1 = sc; cj1 = bj; }
                else                { if (lane == 0) { cv2 = sc; cj2 = bj; } }
            }
        }

        // ---- speculative prefetch of next step's likely parents (all waves) --
        if (step + 1 < NMERGE) {
            prev_p  = p;
            prev_pv = pv;
            prev_nk = nk;
            mm0 = m0; mm1 = m1;
            pvok = (pv >= 0);
            nkok = (nk != 0xFFFF);
            // identity resolution incl. current step (mpos[step]==p != pv,nk)
            unsigned long long bpv = __ballot((lane <= step) && (mpos_reg == pv));
            const int ipv = bpv ? (S_TOT + 63 - __clzll(bpv)) : pv;
            unsigned long long bnk = __ballot((lane <= step) && (mpos_reg == nk));
            const int ink = bnk ? (S_TOT + 63 - __clzll(bnk)) : nk;
            if (pvok) {
                const float4* g = (ipv < S_TOT)
                    ? (const float4*)slot_gptr(ipv, b, bank, refresh)
                    : (const float4*)(merged + ((size_t)b * NMERGE + (ipv - S_TOT)) * D);
                pva0 = g[2 * lane]; pva1 = g[2 * lane + 1];
            }
            if (nkok) {
                const float4* g = (ink < S_TOT)
                    ? (const float4*)slot_gptr(ink, b, bank, refresh)
                    : (const float4*)(merged + ((size_t)b * NMERGE + (ink - S_TOT)) * D);
                pnk0 = g[2 * lane]; pnk1 = g[2 * lane + 1];
            }
        }
        __syncthreads();                     // ---- B2: commit visible to next step ----
    }

    // ---- identity LUT in s_next (dead after main loop) ----
    for (int j = t; j < S_TOT; j += 256) s_next[j] = 0xFFFF;
    __syncthreads();
    if (t == 0)
        for (int m2 = 0; m2 < NMERGE; ++m2) s_next[s_mpos[m2]] = (unsigned short)m2;
    __syncthreads();

    // ---- emit compacted index map ----
    for (int j = t; j < S_TOT; j += 256) {
        if (s_imp[j] < 1e300) {
            int r = j;
            #pragma unroll
            for (int m2 = 0; m2 < NMERGE; ++m2) r -= (s_dead[m2] < j) ? 1 : 0;
            unsigned short lut = s_next[j];
            idx_out[b * S_BANK + r] = (lut != 0xFFFF) ? (unsigned short)(S_TOT + lut)
                                                      : (unsigned short)j;
        }
    }
}

// ---------------- Kernel 3: gather/write output (float4, NT stores) ----------
__global__ __launch_bounds__(256) void gather_kernel(const vfloat4* __restrict__ bank,
        const vfloat4* __restrict__ refresh, const vfloat4* __restrict__ merged,
        const unsigned short* __restrict__ idx, vfloat4* __restrict__ out) {
    size_t tid = (size_t)blockIdx.x * 256 + threadIdx.x;
    int slot = (int)(tid >> 7);
    int c    = (int)(tid & 127);
    int b    = slot >> 13;
    int src  = idx[slot];
    const vfloat4* sp;
    if (src < S_BANK)     sp = bank    + ((size_t)b * S_BANK + src) * (D / 4);
    else if (src < S_TOT) sp = refresh + ((size_t)b * S_REF + (src - S_BANK)) * (D / 4);
    else                  sp = merged  + ((size_t)b * NMERGE + (src - S_TOT)) * (D / 4);
    vfloat4 v = sp[c];
    __builtin_nontemporal_store(v, &out[tid]);
}

// ------------------------------------------------------------------------------
extern "C" void kernel_launch(void* const* d_in, const int* in_sizes, int n_in,
                              void* d_out, int out_size, void* d_ws, size_t ws_size,
                              hipStream_t stream) {
    const float* bank    = (const float*)d_in[0];
    const float* refresh = (const float*)d_in[1];

    double*         norms  = (double*)d_ws;
    float*          merged = (float*)((char*)d_ws + (size_t)B_DIM * S_TOT * sizeof(double));
    unsigned short* idx    = (unsigned short*)((char*)merged + (size_t)B_DIM * NMERGE * D * sizeof(float));
    float*          out    = (float*)d_out;

    norms_kernel<<<(B_DIM * S_TOT) / 4, 256, 0, stream>>>(bank, refresh, norms);
    merge_kernel<<<B_DIM, 256, 0, stream>>>(bank, refresh, norms, merged, idx);
    gather_kernel<<<(size_t)B_DIM * S_BANK * (D / 4) / 256, 256, 0, stream>>>(
        (const vfloat4*)bank, (const vfloat4*)refresh, (const vfloat4*)merged, idx, (vfloat4*)out);
}

// Round 6
// 202.702 us; speedup vs baseline: 4.2599x; 1.0019x over previous
//
#include <hip/hip_runtime.h>
#include <cstdint>
#include <cstddef>

#define B_DIM  16
#define S_BANK 8192
#define S_REF  32
#define S_TOT  8224   // S_BANK + S_REF
#define NMERGE 32     // S_TOT - MAX_SLOTS
#define D      512
#define NCH    129    // ceil(S_TOT / 64)

typedef float vfloat4 __attribute__((ext_vector_type(4)));  // NT-store capable

// Raw workgroup barrier draining ONLY LDS (lgkmcnt), not vmcnt.
// __syncthreads() would emit s_waitcnt vmcnt(0) and confiscate the in-flight
// speculative global prefetch every step. All cross-wave state in the merge
// loop lives in LDS; every global load is consumed by its issuing wave, so
// lgkmcnt(0)+s_barrier gives full release/acquire for the loop's shared data.
__device__ __forceinline__ void wg_barrier_lds() {
    asm volatile("s_waitcnt lgkmcnt(0)" ::: "memory");
    __builtin_amdgcn_s_barrier();
}

// ---------------- DPP wave64 reductions (VALU pipe, no ds_bpermute) ----------
__device__ __forceinline__ int d_lo(double d){ union{double d; int i[2];}u; u.d=d; return u.i[0]; }
__device__ __forceinline__ int d_hi(double d){ union{double d; int i[2];}u; u.d=d; return u.i[1]; }
__device__ __forceinline__ double d_mk(int hi,int lo){ union{double d; int i[2];}u; u.i[0]=lo;u.i[1]=hi; return u.d; }

template<int CTRL>
__device__ __forceinline__ void lex_level(double& v, int& j) {
    // old = self, bound_ctrl = 0: invalid lanes keep own value (lexmin idempotent)
    int lo2 = __builtin_amdgcn_update_dpp(d_lo(v), d_lo(v), CTRL, 0xF, 0xF, false);
    int hi2 = __builtin_amdgcn_update_dpp(d_hi(v), d_hi(v), CTRL, 0xF, 0xF, false);
    int j2  = __builtin_amdgcn_update_dpp(j,       j,       CTRL, 0xF, 0xF, false);
    double v2 = d_mk(hi2, lo2);
    if (v2 < v || (v2 == v && j2 < j)) { v = v2; j = j2; }
}
// lexmin over 64 lanes; result broadcast to all lanes (assoc+comm => exact)
__device__ __forceinline__ void lexmin_wave(double& v, int& j) {
    lex_level<0x111>(v, j);  // row_shr:1
    lex_level<0x112>(v, j);  // row_shr:2
    lex_level<0x114>(v, j);  // row_shr:4
    lex_level<0x118>(v, j);  // row_shr:8
    lex_level<0x142>(v, j);  // row_bcast:15
    lex_level<0x143>(v, j);  // row_bcast:31  -> lane 63 holds lexmin
    int lo = __builtin_amdgcn_readlane(d_lo(v), 63);
    int hi = __builtin_amdgcn_readlane(d_hi(v), 63);
    j      = __builtin_amdgcn_readlane(j, 63);
    v = d_mk(hi, lo);
}
template<int CTRL>
__device__ __forceinline__ void sum_level(double& v) {
    // bound_ctrl = 1: invalid lanes contribute +0.0
    int lo2 = __builtin_amdgcn_update_dpp(0, d_lo(v), CTRL, 0xF, 0xF, true);
    int hi2 = __builtin_amdgcn_update_dpp(0, d_hi(v), CTRL, 0xF, 0xF, true);
    v += d_mk(hi2, lo2);
}
__device__ __forceinline__ double sum_wave(double v) {
    sum_level<0x111>(v); sum_level<0x112>(v); sum_level<0x114>(v);
    sum_level<0x118>(v); sum_level<0x142>(v); sum_level<0x143>(v);
    int lo = __builtin_amdgcn_readlane(d_lo(v), 63);
    int hi = __builtin_amdgcn_readlane(d_hi(v), 63);
    return d_mk(hi, lo);
}

// ---------------- Kernel 1: per-slot L2 norms (f64), reverse order -----------
__global__ __launch_bounds__(256) void norms_kernel(const float* __restrict__ bank,
                                                    const float* __restrict__ refresh,
                                                    double* __restrict__ norms) {
    int gw_lin = (int)((blockIdx.x * 256 + threadIdx.x) >> 6);
    int gw   = B_DIM * S_TOT - 1 - gw_lin;
    int lane = threadIdx.x & 63;
    int b = gw / S_TOT;
    int s = gw - b * S_TOT;
    const float4* src = (const float4*)(s < S_BANK
        ? bank    + ((size_t)b * S_BANK + s) * D
        : refresh + ((size_t)b * S_REF + (s - S_BANK)) * D);
    float4 f0 = src[lane];
    float4 f1 = src[lane + 64];
    double acc = 0.0;
    acc += (double)f0.x * f0.x + (double)f0.y * f0.y + (double)f0.z * f0.z + (double)f0.w * f0.w;
    acc += (double)f1.x * f1.x + (double)f1.y * f1.y + (double)f1.z * f1.z + (double)f1.w * f1.w;
    acc = sum_wave(acc);
    if (lane == 0) norms[gw] = sqrt(acc);
}

// ---------------- Kernel 2: merge-v9 — lgkm-only barriers, early prefetch ----
__device__ __forceinline__ const float* slot_gptr(int id, int b,
        const float* bank, const float* refresh) {
    return (id < S_BANK) ? bank    + ((size_t)b * S_BANK + id) * D
                         : refresh + ((size_t)b * S_REF + (id - S_BANK)) * D;
}

__global__ __launch_bounds__(256) void merge_kernel(const float* __restrict__ bank,
        const float* __restrict__ refresh, const double* __restrict__ norms,
        float* __restrict__ merged, unsigned short* __restrict__ idx_out) {
    __shared__ double         s_imp[S_TOT];      // >=1e300 == dead
    __shared__ unsigned short s_next[S_TOT];     // reused as id-LUT later
    __shared__ float          s_mvec[NMERGE][D]; // merged vectors
    __shared__ unsigned short s_mpos[NMERGE];
    __shared__ unsigned short s_dead[NMERGE];
    __shared__ double c_val[NCH];
    __shared__ int    c_idx[NCH];

    const int t    = threadIdx.x;
    const int b    = blockIdx.x;
    const int lane = t & 63;
    const int wid  = t >> 6;     // 4 waves
    const double INF = __builtin_inf();

    int mpos_reg = -1;           // lane l: position of merge result l (register copy)

    // speculative-prefetch carried state (cascade fast path)
    int prev_p = -1, prev_pv = -1, prev_nk = -1;
    int pvok = 0, nkok = 0;
    float4 mm0, mm1;             // previous merged vector (slot prev_p's current vec)
    float4 pva0, pva1;           // prefetched vector of prev_pv
    float4 pnk0, pnk1;           // prefetched vector of prev_nk

    for (int j = t; j < S_TOT; j += 256) {
        s_imp[j]  = norms[b * S_TOT + j];
        s_next[j] = (unsigned short)((j + 1 < S_TOT) ? (j + 1) : 0xFFFF);
    }
    __syncthreads();

    // initial chunk minima: one thread per chunk, serial scan
    if (t < NCH) {
        int j0 = t * 64;
        int jend = (j0 + 63 < S_TOT - 1) ? (j0 + 63) : (S_TOT - 2);
        double best = INF; int bj = 0x7FFFFFFF;
        for (int j = j0; j <= jend; ++j) {
            double sc = s_imp[j] + s_imp[j + 1];
            if (sc < best) { best = sc; bj = j; }
        }
        c_val[t] = best; c_idx[t] = bj;
    }
    __syncthreads();

    for (int step = 0; step < NMERGE; ++step) {
        // ======== phase A (every wave redundantly; deterministic => agree) ====
        double v = c_val[lane]; int j = c_idx[lane];
        {
            double v2 = c_val[lane + 64]; int j2 = c_idx[lane + 64];
            if (v2 < v || (v2 == v && j2 < j)) { v = v2; j = j2; }
        }
        if (lane == 0) {
            double v3 = c_val[128]; int j3 = c_idx[128];
            if (v3 < v || (v3 == v && j3 < j)) { v = v3; j = j3; }
        }
        lexmin_wave(v, j);
        const int p = j;

        // cascade fast paths: winner involves last step's merged slot
        const bool hitA = pvok && (p == prev_pv);   // pair (prev_pv, prev_p)
        const bool hitB = nkok && (p == prev_p);    // pair (prev_p, prev_nk)

        int k, nk;
        float4 a0, a1, b0, b1;
        if (hitA) {
            k  = prev_p;                 // s_next[prev_pv] == prev_p (list invariant)
            nk = prev_nk;                // s_next[prev_p] == prev_nk (post-commit)
            a0 = pva0; a1 = pva1;        // pv vector: prefetched
            b0 = mm0;  b1 = mm1;         // prev_p vector: carried merged regs
        } else if (hitB) {
            k  = prev_nk;
            nk = s_next[k];              // off critical path (needed for rescan/commit)
            a0 = mm0;  a1 = mm1;
            b0 = pnk0; b1 = pnk1;        // nk vector: prefetched
        } else {
            k  = s_next[p];              // uniform LDS broadcast
            nk = s_next[k];
            // identities from register mpos (no LDS read)
            unsigned long long bA = __ballot((lane < step) && (mpos_reg == p));
            const int ia = bA ? (S_TOT + 63 - __clzll(bA)) : p;
            unsigned long long bB = __ballot((lane < step) && (mpos_reg == k));
            const int ib = bB ? (S_TOT + 63 - __clzll(bB)) : k;
            if (ia < S_TOT) { const float4* g = (const float4*)slot_gptr(ia, b, bank, refresh);
                              a0 = g[2 * lane]; a1 = g[2 * lane + 1]; }
            else            { const float4* g = (const float4*)&s_mvec[ia - S_TOT][0];
                              a0 = g[2 * lane]; a1 = g[2 * lane + 1]; }
            if (ib < S_TOT) { const float4* g = (const float4*)slot_gptr(ib, b, bank, refresh);
                              b0 = g[2 * lane]; b1 = g[2 * lane + 1]; }
            else            { const float4* g = (const float4*)&s_mvec[ib - S_TOT][0];
                              b0 = g[2 * lane]; b1 = g[2 * lane + 1]; }
        }

        // prev-live slot before p (known when hitB; otherwise ballot scan)
        int pv;
        if (hitB) {
            pv = prev_pv;                // nothing between pv and p changed liveness
        } else {
            int jq = p - 1 - lane;
            bool plive = (jq >= 0) && (s_imp[jq] < 1e300);
            unsigned long long pb = __ballot(plive);
            pv = pb ? (p - __ffsll((unsigned long long)pb)) : -1;
        }

        float4 m0, m1;
        m0.x = 0.5f * (a0.x + b0.x); m0.y = 0.5f * (a0.y + b0.y);
        m0.z = 0.5f * (a0.z + b0.z); m0.w = 0.5f * (a0.w + b0.w);
        m1.x = 0.5f * (a1.x + b1.x); m1.y = 0.5f * (a1.y + b1.y);
        m1.z = 0.5f * (a1.z + b1.z); m1.w = 0.5f * (a1.w + b1.w);
        if (wid == 0) {
            float4* dst = (float4*)&s_mvec[step][0];
            dst[2 * lane] = m0; dst[2 * lane + 1] = m1;
        }

        if (lane == step) mpos_reg = p;      // register mpos update (all waves)

        // ---- speculative prefetch of NEXT step's likely parents, issued EARLY:
        //      loads fly under sum_wave+sqrt+B1+commit+rescan+B2 (no vmcnt drain
        //      at the lgkm-only barriers), consumed next step in the hit paths.
        if (step + 1 < NMERGE) {
            prev_p  = p;
            prev_pv = pv;
            prev_nk = nk;
            mm0 = m0; mm1 = m1;
            pvok = (pv >= 0);
            nkok = (nk != 0xFFFF);
            // identity resolution incl. current step (mpos[step]==p != pv,nk,
            // so s_mvec[step] is never read here -> no race with wid0's store)
            unsigned long long bpv = __ballot((lane <= step) && (mpos_reg == pv));
            const int ipv = bpv ? (S_TOT + 63 - __clzll(bpv)) : pv;
            unsigned long long bnk = __ballot((lane <= step) && (mpos_reg == nk));
            const int ink = bnk ? (S_TOT + 63 - __clzll(bnk)) : nk;
            if (pvok) {
                if (ipv < S_TOT) { const float4* g = (const float4*)slot_gptr(ipv, b, bank, refresh);
                                   pva0 = g[2 * lane]; pva1 = g[2 * lane + 1]; }
                else             { const float4* g = (const float4*)&s_mvec[ipv - S_TOT][0];
                                   pva0 = g[2 * lane]; pva1 = g[2 * lane + 1]; }
            }
            if (nkok) {
                if (ink < S_TOT) { const float4* g = (const float4*)slot_gptr(ink, b, bank, refresh);
                                   pnk0 = g[2 * lane]; pnk1 = g[2 * lane + 1]; }
                else             { const float4* g = (const float4*)&s_mvec[ink - S_TOT][0];
                                   pnk0 = g[2 * lane]; pnk1 = g[2 * lane + 1]; }
            }
        }

        double ss = 0.0;
        ss += (double)m0.x * m0.x + (double)m0.y * m0.y + (double)m0.z * m0.z + (double)m0.w * m0.w;
        ss += (double)m1.x * m1.x + (double)m1.y * m1.y + (double)m1.z * m1.z + (double)m1.w * m1.w;
        const double nrm = sqrt(sum_wave(ss));
        wg_barrier_lds();                    // ---- B1 (lgkm only) ----

        // ======== phase B ====================================================
        if (wid == 3 && lane == 0) {         // commit (concurrent with rescans)
            s_next[p]    = (unsigned short)nk;
            s_imp[k]     = INF;
            s_imp[p]     = nrm;
            s_mpos[step] = (unsigned short)p;
            s_dead[step] = (unsigned short)k;
        }

        if (wid < 3) {                       // rescan affected chunks, stale LDS
            int chp = p >> 6, chk = k >> 6;  // + in-register substitutions
            int chv = (pv >= 0) ? (pv >> 6) : -1;
            int cs = (wid == 0) ? chp
                   : (wid == 1) ? ((chk != chp) ? chk : -1)
                                : ((chv >= 0 && chv != chp && chv != chk) ? chv : -1);
            if (cs >= 0) {
                double sc = INF; int bj = 0x7FFFFFFF;
                int jj = cs * 64 + lane;
                if (jj < S_TOT && jj != k) {
                    int nxt = (jj == p) ? nk : (int)s_next[jj];
                    if (nxt != 0xFFFF) {
                        double a0d = (jj == p) ? nrm : s_imp[jj];
                        if (a0d < 1e300) {
                            double a1d = (nxt == p) ? nrm : s_imp[nxt];
                            sc = a0d + a1d; bj = jj;
                        }
                    }
                }
                lexmin_wave(sc, bj);
                if (lane == 0) { c_val[cs] = sc; c_idx[cs] = bj; }
            }
        }
        wg_barrier_lds();                    // ---- B2 (lgkm only) ----
    }

    __syncthreads();   // full barrier (vmcnt too) before epilogue reuse

    // ---- dump merged vectors to global for the gather ----
    {
        const float4* src = (const float4*)&s_mvec[0][0];
        float4* dst = (float4*)(merged + (size_t)b * NMERGE * D);
        for (int i = t; i < NMERGE * D / 4; i += 256) dst[i] = src[i];
    }

    // ---- identity LUT in s_next (dead after main loop) ----
    for (int j = t; j < S_TOT; j += 256) s_next[j] = 0xFFFF;
    __syncthreads();
    if (t == 0)
        for (int m2 = 0; m2 < NMERGE; ++m2) s_next[s_mpos[m2]] = (unsigned short)m2;
    __syncthreads();

    // ---- emit compacted index map ----
    for (int j = t; j < S_TOT; j += 256) {
        if (s_imp[j] < 1e300) {
            int r = j;
            #pragma unroll
            for (int m2 = 0; m2 < NMERGE; ++m2) r -= (s_dead[m2] < j) ? 1 : 0;
            unsigned short lut = s_next[j];
            idx_out[b * S_BANK + r] = (lut != 0xFFFF) ? (unsigned short)(S_TOT + lut)
                                                      : (unsigned short)j;
        }
    }
}

// ---------------- Kernel 3: gather/write output (float4, NT stores) ----------
__global__ __launch_bounds__(256) void gather_kernel(const vfloat4* __restrict__ bank,
        const vfloat4* __restrict__ refresh, const vfloat4* __restrict__ merged,
        const unsigned short* __restrict__ idx, vfloat4* __restrict__ out) {
    size_t tid = (size_t)blockIdx.x * 256 + threadIdx.x;
    int slot = (int)(tid >> 7);
    int c    = (int)(tid & 127);
    int b    = slot >> 13;
    int src  = idx[slot];
    const vfloat4* sp;
    if (src < S_BANK)     sp = bank    + ((size_t)b * S_BANK + src) * (D / 4);
    else if (src < S_TOT) sp = refresh + ((size_t)b * S_REF + (src - S_BANK)) * (D / 4);
    else                  sp = merged  + ((size_t)b * NMERGE + (src - S_TOT)) * (D / 4);
    vfloat4 v = sp[c];
    __builtin_nontemporal_store(v, &out[tid]);
}

// ------------------------------------------------------------------------------
extern "C" void kernel_launch(void* const* d_in, const int* in_sizes, int n_in,
                              void* d_out, int out_size, void* d_ws, size_t ws_size,
                              hipStream_t stream) {
    const float* bank    = (const float*)d_in[0];
    const float* refresh = (const float*)d_in[1];

    double*         norms  = (double*)d_ws;
    float*          merged = (float*)((char*)d_ws + (size_t)B_DIM * S_TOT * sizeof(double));
    unsigned short* idx    = (unsigned short*)((char*)merged + (size_t)B_DIM * NMERGE * D * sizeof(float));
    float*          out    = (float*)d_out;

    norms_kernel<<<(B_DIM * S_TOT) / 4, 256, 0, stream>>>(bank, refresh, norms);
    merge_kernel<<<B_DIM, 256, 0, stream>>>(bank, refresh, norms, merged, idx);
    gather_kernel<<<(size_t)B_DIM * S_BANK * (D / 4) / 256, 256, 0, stream>>>(
        (const vfloat4*)bank, (const vfloat4*)refresh, (const vfloat4*)merged, idx, (vfloat4*)out);
}